// Round 7
// baseline (442.976 us; speedup 1.0000x reference)
//
#include <hip/hip_runtime.h>
#include <math.h>

typedef __attribute__((ext_vector_type(8))) short short8;
typedef __attribute__((ext_vector_type(4))) float f32x4;
typedef __attribute__((ext_vector_type(4))) unsigned int uint4v;

#define HIDDEN 1024
#define QOUT 2048
#define KVOUT 1024
#define HD 128
#define TSEQ 2048

__device__ __forceinline__ float bf2f(unsigned short h) {
    union { unsigned int u; float f; } x; x.u = ((unsigned int)h) << 16; return x.f;
}
__device__ __forceinline__ unsigned short f2bf(float f) {
    union { float f; unsigned int u; } x; x.f = f;
    unsigned int r = (x.u + 0x7fffu + ((x.u >> 16) & 1u)) >> 16;
    return (unsigned short)r;
}
// HW packed f32->bf16 (RNE, same semantics as f2bf pair) -- 1 VALU op per 2 values
__device__ __forceinline__ unsigned int cvtpk(float lo, float hi) {
    unsigned int r;
    asm("v_cvt_pk_bf16_f32 %0, %1, %2" : "=v"(r) : "v"(lo), "v"(hi));
    return r;
}
// gfx950 cross-lane swaps (VALU pipe -- no LDS):
// pl32: a' = [a.lanes0-31 | b.lanes0-31], b' = [a.lanes32-63 | b.lanes32-63]
// pl16: a' = [a.q0, b.q0, a.q2, b.q2],    b' = [a.q1, b.q1, a.q3, b.q3]   (q = 16-lane quad)
__device__ __forceinline__ void pl32(unsigned int& a, unsigned int& b) {
    asm("v_permlane32_swap_b32 %0, %1" : "+v"(a), "+v"(b));
}
__device__ __forceinline__ void pl16(unsigned int& a, unsigned int& b) {
    asm("v_permlane16_swap_b32 %0, %1" : "+v"(a), "+v"(b));
}

// async global->LDS, 16B per lane; dest = wave-uniform base + lane*16
__device__ __forceinline__ void glds16(const unsigned short* g, unsigned short* l) {
    __builtin_amdgcn_global_load_lds(
        (const __attribute__((address_space(1))) unsigned int*)g,
        (__attribute__((address_space(3))) unsigned int*)l, 16, 0, 0);
}

// ---------------- prep: cast x->bf16  +  4 weight transposes (fp32 KxN -> bf16 NxK) ---------
__global__ __launch_bounds__(256) void prep(const float* __restrict__ x,
                                            const float* __restrict__ Wq,
                                            const float* __restrict__ Wk,
                                            const float* __restrict__ Wv,
                                            const float* __restrict__ Wo,
                                            unsigned short* __restrict__ xb,
                                            unsigned short* __restrict__ Wt,
                                            unsigned short* __restrict__ Wot) {
    int bid = blockIdx.x;
    int tid = threadIdx.x;
    if (bid < 4096) {  // cast: 1M float4
        int i = bid * 256 + tid;
        float4 v = *(const float4*)(x + (size_t)i * 4);
        unsigned short o[4] = {f2bf(v.x), f2bf(v.y), f2bf(v.z), f2bf(v.w)};
        *(unsigned long long*)(xb + (size_t)i * 4) = *(unsigned long long*)o;
        return;
    }
    bid -= 4096;
    const float* W; unsigned short* D; int K, N;
    if (bid < 512)       { W = Wq; D = Wt;                          K = 1024; N = 2048; }
    else if (bid < 768)  { bid -= 512;  W = Wk; D = Wt + (size_t)2048 * 1024; K = 1024; N = 1024; }
    else if (bid < 1024) { bid -= 768;  W = Wv; D = Wt + (size_t)3072 * 1024; K = 1024; N = 1024; }
    else                 { bid -= 1024; W = Wo; D = Wot;                      K = 2048; N = 1024; }
    __shared__ __attribute__((aligned(16))) unsigned short Ls[64 * 72];
    int ntiles = N >> 6;
    int kt = bid / ntiles, nt = bid - kt * ntiles;
    int k0 = kt * 64, n0 = nt * 64;
    for (int t = 0; t < 4; t++) {
        int idx = tid + t * 256;
        int r = idx >> 4, seg = idx & 15;
        float4 v = *(const float4*)(W + (size_t)(k0 + r) * N + n0 + seg * 4);
        int c = seg * 4;
        Ls[(c + 0) * 72 + r] = f2bf(v.x);
        Ls[(c + 1) * 72 + r] = f2bf(v.y);
        Ls[(c + 2) * 72 + r] = f2bf(v.z);
        Ls[(c + 3) * 72 + r] = f2bf(v.w);
    }
    __syncthreads();
    for (int t = 0; t < 2; t++) {
        int idx = tid + t * 256;
        int rr = idx >> 3, seg = idx & 7;
        uint4v v = *(const uint4v*)(Ls + rr * 72 + seg * 8);
        *(uint4v*)(D + (size_t)(n0 + rr) * K + k0 + seg * 8) = v;
    }
}

// ---------------- GEMM (QKV): C[M,N] = A[M,K](bf16) @ Bt[N,K]^T(bf16), BK=32, BN=128 --------
// Round-5 lesson: BN=64/BK=64 regressed this shape (2x blocks -> +50% panel traffic);
// this BN=128/BK=32 form is the measured best for the QKV projection.
template <int OUT_BF16, int BN>
__global__ __launch_bounds__(256) void gemm_bt(const unsigned short* __restrict__ A,
                                               const unsigned short* __restrict__ Bt,
                                               void* __restrict__ Cout,
                                               int M, int N, int K) {
    constexpr int MT = (BN == 128) ? 4 : 2;
    __shared__ __attribute__((aligned(16))) unsigned short As[2][128 * 32];
    __shared__ __attribute__((aligned(16))) unsigned short Bs[2][BN * 32];
    const int tid = threadIdx.x;
    const int lane = tid & 63;
    const int warp = tid >> 6;
    const int ln = lane & 15;
    const int quad = lane >> 4;
    const int wm = (BN == 128) ? (warp >> 1) : warp;
    const int wn = (BN == 128) ? (warp & 1) : 0;
    const int m0 = blockIdx.y * 128;
    const int n0 = blockIdx.x * BN;

    const int srow = lane >> 2;
    const int schunk = (lane & 3) ^ (srow & 3);
    const unsigned short* Ag = A + (size_t)(m0 + warp * 16 + srow) * K + schunk * 8;
    const unsigned short* Bg = Bt + (size_t)(n0 + warp * 16 + srow) * K + schunk * 8;

    f32x4 acc[MT][4];
#pragma unroll
    for (int i = 0; i < MT; i++)
#pragma unroll
        for (int j = 0; j < 4; j++) acc[i][j] = (f32x4){0.f, 0.f, 0.f, 0.f};

    auto stage = [&](int k0, int bi) {
        glds16(Ag + k0, As[bi] + warp * 16 * 32);
        glds16(Ag + (size_t)64 * K + k0, As[bi] + warp * 16 * 32 + 64 * 32);
        glds16(Bg + k0, Bs[bi] + warp * 16 * 32);
        if (BN == 128) glds16(Bg + (size_t)64 * K + k0, Bs[bi] + warp * 16 * 32 + 64 * 32);
    };

    const int rq = quad ^ (ln & 3);   // swizzled read chunk
    const int KI = K >> 5;
    stage(0, 0);
    for (int it = 0; it < KI; it++) {
        __syncthreads();            // drains my glds for buf it&1
        if (it + 1 < KI) stage((it + 1) << 5, (it + 1) & 1);
        const unsigned short* Ab = As[it & 1];
        const unsigned short* Bb = Bs[it & 1];
        short8 af[MT], bf[4];
#pragma unroll
        for (int mt = 0; mt < MT; mt++)
            af[mt] = *(const short8*)(Ab + (wm * (MT * 16) + mt * 16 + ln) * 32 + rq * 8);
#pragma unroll
        for (int nt = 0; nt < 4; nt++)
            bf[nt] = *(const short8*)(Bb + (wn * 64 + nt * 16 + ln) * 32 + rq * 8);
#pragma unroll
        for (int mt = 0; mt < MT; mt++)
#pragma unroll
            for (int nt = 0; nt < 4; nt++)
                acc[mt][nt] = __builtin_amdgcn_mfma_f32_16x16x32_bf16(bf[nt], af[mt], acc[mt][nt], 0, 0, 0);
    }
#pragma unroll
    for (int mt = 0; mt < MT; mt++) {
        int row = m0 + wm * (MT * 16) + mt * 16 + ln;
#pragma unroll
        for (int nt = 0; nt < 4; nt++) {
            int colb = n0 + wn * 64 + nt * 16 + quad * 4;
            if (OUT_BF16) {
                unsigned long long pk =
                    (unsigned long long)cvtpk(acc[mt][nt][0], acc[mt][nt][1]) |
                    ((unsigned long long)cvtpk(acc[mt][nt][2], acc[mt][nt][3]) << 32);
                *(unsigned long long*)((unsigned short*)Cout + (size_t)row * N + colb) = pk;
            } else {
                *(f32x4*)((float*)Cout + (size_t)row * N + colb) = acc[mt][nt];
            }
        }
    }
}

// ---------------- GEMM (O-proj): BM=128, BN=64, BK=64 -- round-2 measured win -------------
template <int OUT_BF16>
__global__ __launch_bounds__(256) void gemm_o(const unsigned short* __restrict__ A,
                                              const unsigned short* __restrict__ Bt,
                                              void* __restrict__ Cout,
                                              int M, int N, int K) {
    __shared__ __attribute__((aligned(16))) unsigned short As[2][128 * 64];  // 32 KB
    __shared__ __attribute__((aligned(16))) unsigned short Bs[2][64 * 64];   // 16 KB
    const int tid = threadIdx.x;
    const int lane = tid & 63;
    const int warp = tid >> 6;
    const int ln = lane & 15;
    const int quad = lane >> 4;
    const int m0 = blockIdx.y * 128;
    const int n0 = blockIdx.x * 64;

    const int srow = lane >> 3;            // 0..7
    const int schunk = (lane & 7) ^ srow;  // inverse-swizzled source chunk
    const unsigned short* Ag = A + (size_t)(m0 + warp * 32 + srow) * K + schunk * 8;
    const unsigned short* Bg = Bt + (size_t)(n0 + warp * 16 + srow) * K + schunk * 8;

    f32x4 acc[2][4];
#pragma unroll
    for (int i = 0; i < 2; i++)
#pragma unroll
        for (int j = 0; j < 4; j++) acc[i][j] = (f32x4){0.f, 0.f, 0.f, 0.f};

    auto stage = [&](int k0, int bi) {
#pragma unroll
        for (int g = 0; g < 4; g++)   // A rows warp*32 + g*8 + srow
            glds16(Ag + (size_t)(g * 8) * K + k0, As[bi] + (warp * 32 + g * 8) * 64);
#pragma unroll
        for (int g = 0; g < 2; g++)   // B rows warp*16 + g*8 + srow
            glds16(Bg + (size_t)(g * 8) * K + k0, Bs[bi] + (warp * 16 + g * 8) * 64);
    };

    const int KI = K >> 6;
    stage(0, 0);
    for (int it = 0; it < KI; it++) {
        __syncthreads();            // drains my glds for buf it&1
        if (it + 1 < KI) stage((it + 1) << 6, (it + 1) & 1);
        const unsigned short* Ab = As[it & 1];
        const unsigned short* Bb = Bs[it & 1];
#pragma unroll
        for (int ks = 0; ks < 2; ks++) {
            const int rc = ((ks << 2) + quad) ^ (ln & 7);
            short8 af[2], bf[4];
#pragma unroll
            for (int mt = 0; mt < 2; mt++)
                af[mt] = *(const short8*)(Ab + (warp * 32 + mt * 16 + ln) * 64 + rc * 8);
#pragma unroll
            for (int nt = 0; nt < 4; nt++)
                bf[nt] = *(const short8*)(Bb + (nt * 16 + ln) * 64 + rc * 8);
#pragma unroll
            for (int mt = 0; mt < 2; mt++)
#pragma unroll
                for (int nt = 0; nt < 4; nt++)
                    acc[mt][nt] = __builtin_amdgcn_mfma_f32_16x16x32_bf16(bf[nt], af[mt], acc[mt][nt], 0, 0, 0);
        }
    }
#pragma unroll
    for (int mt = 0; mt < 2; mt++) {
        int row = m0 + warp * 32 + mt * 16 + ln;
#pragma unroll
        for (int nt = 0; nt < 4; nt++) {
            int colb = n0 + nt * 16 + quad * 4;
            if (OUT_BF16) {
                unsigned long long pk =
                    (unsigned long long)cvtpk(acc[mt][nt][0], acc[mt][nt][1]) |
                    ((unsigned long long)cvtpk(acc[mt][nt][2], acc[mt][nt][3]) << 32);
                *(unsigned long long*)((unsigned short*)Cout + (size_t)row * N + colb) = pk;
            } else {
                *(f32x4*)((float*)Cout + (size_t)row * N + colb) = acc[mt][nt];
            }
        }
    }
}

// ---------------- fused norm_rope (blocks < 12288) + v_transpose (rest) ----------------
__global__ __launch_bounds__(256) void nrvt(const unsigned short* __restrict__ QKV,
                                            const float* __restrict__ qw,
                                            const float* __restrict__ kw,
                                            unsigned short* __restrict__ Q,
                                            unsigned short* __restrict__ Kb,
                                            unsigned short* __restrict__ Vt) {
    if (blockIdx.x < 12288) {
        const int tid = threadIdx.x;
        const int l5 = tid & 31;
        const int task = blockIdx.x * 8 + (tid >> 5);   // 98304 tasks
        const int tok = task / 24;
        const int slot = task - tok * 24;
        const int b = tok >> 11, t = tok & 2047;
        const float* w;
        unsigned short* dst;
        int col0;
        float sc;
        if (slot < 16) {
            col0 = slot * HD;
            dst = Q + ((size_t)(b * 16 + slot) * TSEQ + t) * HD;
            w = qw;
            sc = 0.12750580997495268f;  // (1/sqrt(128)) * log2(e) folded into Q
        } else {
            int hk = slot - 16;
            col0 = QOUT + hk * HD;
            dst = Kb + ((size_t)(b * 8 + hk) * TSEQ + t) * HD;
            w = kw;
            sc = 1.0f;
        }
        const unsigned short* row = QKV + (size_t)tok * 4096 + col0;
        unsigned long long pkin = *(const unsigned long long*)(row + l5 * 4);
        unsigned short us[4];
        *(unsigned long long*)us = pkin;
        float e[4];
        float ss = 0.f;
#pragma unroll
        for (int k = 0; k < 4; k++) { e[k] = bf2f(us[k]); ss += e[k] * e[k]; }
#pragma unroll
        for (int off = 1; off < 32; off <<= 1) ss += __shfl_xor(ss, off);
        float rr = rsqrtf(ss * (1.0f / 128.0f) + 1e-6f);
        float4 wv = *(const float4*)(w + l5 * 4);
        float n[4] = { e[0] * rr * wv.x, e[1] * rr * wv.y, e[2] * rr * wv.z, e[3] * rr * wv.w };
        float np[4];
#pragma unroll
        for (int k = 0; k < 4; k++) np[k] = __shfl_xor(n[k], 16);
        const float tf = (float)t;
        const int fb = (l5 & 15) * 4;      // freq index base = d % 64
        const bool hi = (l5 >= 16);
        unsigned short outs[4];
#pragma unroll
        for (int k = 0; k < 4; k++) {
            float invf = __builtin_exp2f(-(float)(fb + k) * 0.20762050593045951f);
            float sf, cf;
            __sincosf(tf * invf, &sf, &cf);
            float o = hi ? (n[k] * cf + np[k] * sf) : (n[k] * cf - np[k] * sf);
            outs[k] = f2bf(o * sc);
        }
        *(unsigned long long*)(dst + l5 * 4) = *(unsigned long long*)outs;
        return;
    }
    // v_transpose
    __shared__ __attribute__((aligned(16))) unsigned short Ls[128 * 72];
    int bid = blockIdx.x - 12288;
    int tt = bid & 31, hk = (bid >> 5) & 7, b = bid >> 8;
    int t0 = tt * 64;
    int tid = threadIdx.x;
    const unsigned short* base = QKV + (size_t)(b * 2048 + t0) * 4096 + 3072 + hk * 128;
    for (int i = 0; i < 4; i++) {
        int idx = tid + i * 256;
        int r = idx >> 4, seg = idx & 15;
        uint4v v = *(const uint4v*)(base + (size_t)r * 4096 + seg * 8);
        unsigned short* pv = (unsigned short*)&v;
        int d = seg * 8;
        for (int jj = 0; jj < 8; jj++) Ls[(d + jj) * 72 + r] = pv[jj];
    }
    __syncthreads();
    unsigned short* out = Vt + (size_t)(b * 8 + hk) * 128 * 2048;
    for (int i = 0; i < 4; i++) {
        int idx = tid + i * 256;
        int d = idx >> 3, seg = idx & 7;
        uint4v v = *(const uint4v*)(Ls + d * 72 + seg * 8);
        *(uint4v*)(out + (size_t)d * 2048 + t0 + seg * 8) = v;
    }
}

// ---------------- flash attention v12: KVBLK=32, 32 KB LDS, 4 blocks/CU, 32 waves/CU -------
// v11 post-mortem: conflict-free + 19% less LDS traffic gave 0 -> NOT LDS-bound; all pipes
// <45% at 4 waves/SIMD -> latency-bound with barrier-lockstep waves. v12 doubles TLP and
// independent-block count: KV tile 32 (Ks 2x8KB + packed Vs 2x8KB = 32KB -> 4 blocks/CU),
// __launch_bounds__(512,8) pins 8 waves/SIMD (v11 used 56 VGPR; v12 halves transients).
// Per-kv work unchanged; iters double (nT = 64-2p). Vs packs TWO d-rows per 128B LDS row
// (row=d>>1, col=(d&1)*32+kv) so the proven 8-chunk XOR swizzle stays conflict-free at
// the 64B-per-d granularity. act = (j<=jdiag) uniformly (also skips the fully-masked last
// half-tile for wi<2 sg1 waves).
__global__ __launch_bounds__(512, 8) void attn(const unsigned short* __restrict__ Q,
                                               const unsigned short* __restrict__ Kg,
                                               const unsigned short* __restrict__ Vt,
                                               unsigned short* __restrict__ Og) {
    __shared__ __attribute__((aligned(16))) unsigned short Ks[2][32 * 128];  // swizzled (kv, d)
    __shared__ __attribute__((aligned(16))) unsigned short Vs[2][64 * 64];   // packed (d>>1, (d&1)*32+kv)
    const int p = blockIdx.x;
    const int bh = blockIdx.y;
    const int b = bh >> 4, h = bh & 15, hk = h >> 1;
    const int tid = threadIdx.x;
    const int w = tid >> 6, lane = tid & 63, ln = lane & 15, quad = lane >> 4;
    const int sg = w >> 2;                    // strip group: 0 -> tile p, 1 -> tile 31-p
    const int wi = w & 3;
    const int tile = sg ? (31 - p) : p;       // 64-row q-tile index
    const int jdiag = 2 * tile + (wi >> 1);   // kv-half-tile index where the diagonal falls
    const int qrow0 = tile * 64 + wi * 16;    // this wave's 16 q-rows

    const unsigned short* Kbase = Kg + (size_t)(b * 8 + hk) * TSEQ * HD;
    const unsigned short* Vbase = Vt + (size_t)(b * 8 + hk) * HD * TSEQ;
    const unsigned short* Qh = Q + (size_t)(b * 16 + h) * TSEQ * HD;

    short8 qf[4];
#pragma unroll
    for (int kt = 0; kt < 4; kt++)
        qf[kt] = *(const short8*)(Qh + (size_t)(qrow0 + ln) * HD + kt * 32 + quad * 8);

    f32x4 o[8];
    f32x4 lac = (f32x4){0.f, 0.f, 0.f, 0.f};
#pragma unroll
    for (int ot = 0; ot < 8; ot++) o[ot] = (f32x4){0.f, 0.f, 0.f, 0.f};
    float m_ = -1e30f;

    // staging (per wave, per tile: 1 glds K + 1 glds V = 16B/lane each)
    // K: rows w*4+(lane>>4) of 32, chunk (lane&15), src chunk = (lane&15)^(row&15)
    // V: LDS row r = w*8+(lane>>3) (holds d=2r,2r+1), pos = lane&7, logical chunk
    //    c = pos^(r&7); c -> d = 2r+(c>>2), kv = (c&3)*8
    auto stage_kv = [&](int jt, int bi) {
        const int j0s = jt * 32;
        {
            int row = w * 4 + (lane >> 4);
            int kchunk = lane & 15;
            glds16(Kbase + (size_t)(j0s + row) * HD + ((kchunk ^ (row & 15)) * 8),
                   Ks[bi] + (w * 4) * 128);
        }
        {
            int r = w * 8 + (lane >> 3);
            int c = (lane & 7) ^ (r & 7);
            glds16(Vbase + (size_t)(2 * r + (c >> 2)) * TSEQ + j0s + (c & 3) * 8,
                   Vs[bi] + (w * 8) * 64);
        }
    };

    // bf16 1.0 fragment for row-sum MFMA (B = all-ones 16x32)
    short8 ones8;
#pragma unroll
    for (int i = 0; i < 8; i++) ones8[i] = (short)0x3F80;

    const int nT = 64 - 2 * p;
    stage_kv(0, 0);
    for (int j = 0; j < nT; j++) {
        __syncthreads();                 // drains my glds for buf j&1 (prev iter's prefetch)
        if (j + 1 < nT) stage_kv(j + 1, (j + 1) & 1);
        const unsigned short* KsC = Ks[j & 1];
        const unsigned short* VsC = Vs[j & 1];
        if (j <= jdiag) {
            // ---- QK^T: S 16q x 32kv (Q pre-scaled: s is in exp2 domain) ----
            f32x4 s[2];
            s[0] = (f32x4){0.f, 0.f, 0.f, 0.f};
            s[1] = (f32x4){0.f, 0.f, 0.f, 0.f};
            __builtin_amdgcn_s_setprio(1);
#pragma unroll
            for (int kt = 0; kt < 4; kt++) {
                short8 kf[2];
#pragma unroll
                for (int kb = 0; kb < 2; kb++)
                    kf[kb] = *(const short8*)(KsC + (kb * 16 + ln) * 128 + (((kt * 4 + quad) ^ ln) * 8));
#pragma unroll
                for (int kb = 0; kb < 2; kb++)
                    s[kb] = __builtin_amdgcn_mfma_f32_16x16x32_bf16(kf[kb], qf[kt], s[kb], 0, 0, 0);
            }
            __builtin_amdgcn_s_setprio(0);
            // ---- softmax: defer-max (THR=8), shuffle-free common path ----
            if (j == jdiag) {
                const int qrel = wi * 16 + ln - ((wi >> 1) << 5);   // 0..31
#pragma unroll
                for (int kb = 0; kb < 2; kb++)
#pragma unroll
                    for (int r = 0; r < 4; r++) {
                        int kvl = kb * 16 + quad * 4 + r;
                        if (kvl > qrel) s[kb][r] = -1e30f;
                    }
            }
            float mk0 = fmaxf(fmaxf(s[0][0], s[0][1]), fmaxf(s[0][2], s[0][3]));
            float mk1 = fmaxf(fmaxf(s[1][0], s[1][1]), fmaxf(s[1][2], s[1][3]));
            float mx = fmaxf(mk0, mk1);
            float mn = m_;
            bool needR = false;
            float alpha = 1.f;
            if (!__all(mx <= mn + 8.0f)) {
                mx = fmaxf(mx, __shfl_xor(mx, 16));
                mx = fmaxf(mx, __shfl_xor(mx, 32));
                mn = fmaxf(m_, mx);
                alpha = __builtin_exp2f(m_ - mn);
                m_ = mn;
                needR = true;
            }
            // ---- P -> bf16 packed, then VALU quad-crossbar (no LDS) ----
            unsigned int u[4];
#pragma unroll
            for (int kb = 0; kb < 2; kb++) {
                float p0 = __builtin_exp2f(s[kb][0] - mn);
                float p1 = __builtin_exp2f(s[kb][1] - mn);
                float p2 = __builtin_exp2f(s[kb][2] - mn);
                float p3 = __builtin_exp2f(s[kb][3] - mn);
                u[kb * 2 + 0] = cvtpk(p0, p1);   // kv = 16kb + 4*quad + {0,1}, q = ln
                u[kb * 2 + 1] = cvtpk(p2, p3);   // kv = 16kb + 4*quad + {2,3}
            }
            pl32(u[0], u[2]); pl16(u[0], u[2]);
            pl32(u[1], u[3]); pl16(u[1], u[3]);
            union { unsigned int uu[4]; short8 s8; } P0;
            P0.uu[0] = u[0]; P0.uu[1] = u[1]; P0.uu[2] = u[2]; P0.uu[3] = u[3];
            short8 pf = P0.s8;   // P[kv = 8*quad + {0..7}][q = ln]
            // ---- rescale O and l (uniform branch, rare after first tile) ----
            if (needR) {
#pragma unroll
                for (int ot = 0; ot < 8; ot++)
#pragma unroll
                    for (int r = 0; r < 4; r++) o[ot][r] *= alpha;
#pragma unroll
                for (int r = 0; r < 4; r++) lac[r] *= alpha;
            }
            // ---- PV + row-sum; operand-swapped (O: col=q=ln, rows=d) ----
            __builtin_amdgcn_s_setprio(1);
            lac = __builtin_amdgcn_mfma_f32_16x16x32_bf16(ones8, pf, lac, 0, 0, 0);
#pragma unroll
            for (int ot = 0; ot < 8; ot++) {
                int vrow = ot * 8 + (ln >> 1);
                int cc = (((ln & 1) << 2) + quad) ^ (vrow & 7);
                short8 vf = *(const short8*)(VsC + vrow * 64 + cc * 8);
                o[ot] = __builtin_amdgcn_mfma_f32_16x16x32_bf16(vf, pf, o[ot], 0, 0, 0);
            }
            __builtin_amdgcn_s_setprio(0);
        }
    }
    // epilogue: lane has q = qrow0+ln; regs are 4 consecutive d -> 8B stores
    float inv = 1.0f / lac[0];
    size_t rowoff = ((size_t)(b * TSEQ + qrow0 + ln)) * QOUT + h * 128 + quad * 4;
#pragma unroll
    for (int ot = 0; ot < 8; ot++) {
        unsigned long long pk =
            (unsigned long long)cvtpk(o[ot][0] * inv, o[ot][1] * inv) |
            ((unsigned long long)cvtpk(o[ot][2] * inv, o[ot][3] * inv) << 32);
        *(unsigned long long*)(Og + rowoff + ot * 16) = pk;
    }
}

extern "C" void kernel_launch(void* const* d_in, const int* in_sizes, int n_in,
                              void* d_out, int out_size, void* d_ws, size_t ws_size,
                              hipStream_t stream) {
    (void)in_sizes; (void)n_in; (void)out_size;
    const float* x  = (const float*)d_in[0];
    const float* Wq = (const float*)d_in[1];
    const float* Wk = (const float*)d_in[2];
    const float* Wv = (const float*)d_in[3];
    const float* Wo = (const float*)d_in[4];
    const float* qw = (const float*)d_in[5];
    const float* kw = (const float*)d_in[6];

    char* ws = (char*)d_ws;
    const size_t MB = 1024 * 1024;
    unsigned short* Wt   = (unsigned short*)(ws);            // 8 MB
    unsigned short* Wot  = (unsigned short*)(ws + 8 * MB);   // 4 MB
    unsigned short* QKVb = (unsigned short*)(ws + 12 * MB);  // 32 MB (bf16)
    unsigned short* xb   = (unsigned short*)(ws + 44 * MB);  // 8 MB
    unsigned short* Qb   = (unsigned short*)(ws + 52 * MB);  // 16 MB
    unsigned short* Kb   = (unsigned short*)(ws + 68 * MB);  // 8 MB
    unsigned short* Vtb  = (unsigned short*)(ws + 76 * MB);  // 8 MB
    unsigned short* Ob   = (unsigned short*)(ws + 84 * MB);  // 16 MB
    if (ws_size < 100 * MB) return;

    prep<<<dim3(5632), 256, 0, stream>>>(x, Wq, Wk, Wv, Wo, xb, Wt, Wot);
    gemm_bt<1, 128><<<dim3(32, 32), 256, 0, stream>>>(xb, Wt, QKVb, 4096, 4096, 1024);
    nrvt<<<dim3(12800), 256, 0, stream>>>(QKVb, qw, kw, Qb, Kb, Vtb);
    attn<<<dim3(16, 32), 512, 0, stream>>>(Qb, Kb, Vtb, Ob);
    gemm_o<0><<<dim3(16, 32), 256, 0, stream>>>(Ob, Wot, (float*)d_out, 4096, 1024, 2048);
}

// Round 8
// 248.133 us; speedup vs baseline: 1.7852x; 1.7852x over previous
//
#include <hip/hip_runtime.h>
#include <math.h>

typedef __attribute__((ext_vector_type(8))) short short8;
typedef __attribute__((ext_vector_type(4))) float f32x4;
typedef __attribute__((ext_vector_type(4))) unsigned int uint4v;

#define HIDDEN 1024
#define QOUT 2048
#define KVOUT 1024
#define HD 128
#define TSEQ 2048

__device__ __forceinline__ float bf2f(unsigned short h) {
    union { unsigned int u; float f; } x; x.u = ((unsigned int)h) << 16; return x.f;
}
__device__ __forceinline__ unsigned short f2bf(float f) {
    union { float f; unsigned int u; } x; x.f = f;
    unsigned int r = (x.u + 0x7fffu + ((x.u >> 16) & 1u)) >> 16;
    return (unsigned short)r;
}
// HW packed f32->bf16 (RNE, same semantics as f2bf pair) -- 1 VALU op per 2 values
__device__ __forceinline__ unsigned int cvtpk(float lo, float hi) {
    unsigned int r;
    asm("v_cvt_pk_bf16_f32 %0, %1, %2" : "=v"(r) : "v"(lo), "v"(hi));
    return r;
}
// gfx950 cross-lane swaps (VALU pipe -- no LDS):
// pl32: a' = [a.lanes0-31 | b.lanes0-31], b' = [a.lanes32-63 | b.lanes32-63]
// pl16: a' = [a.q0, b.q0, a.q2, b.q2],    b' = [a.q1, b.q1, a.q3, b.q3]   (q = 16-lane quad)
__device__ __forceinline__ void pl32(unsigned int& a, unsigned int& b) {
    asm("v_permlane32_swap_b32 %0, %1" : "+v"(a), "+v"(b));
}
__device__ __forceinline__ void pl16(unsigned int& a, unsigned int& b) {
    asm("v_permlane16_swap_b32 %0, %1" : "+v"(a), "+v"(b));
}

// async global->LDS, 16B per lane; dest = wave-uniform base + lane*16
__device__ __forceinline__ void glds16(const unsigned short* g, unsigned short* l) {
    __builtin_amdgcn_global_load_lds(
        (const __attribute__((address_space(1))) unsigned int*)g,
        (__attribute__((address_space(3))) unsigned int*)l, 16, 0, 0);
}

// ---------------- prep: cast x->bf16  +  4 weight transposes (fp32 KxN -> bf16 NxK) ---------
__global__ __launch_bounds__(256) void prep(const float* __restrict__ x,
                                            const float* __restrict__ Wq,
                                            const float* __restrict__ Wk,
                                            const float* __restrict__ Wv,
                                            const float* __restrict__ Wo,
                                            unsigned short* __restrict__ xb,
                                            unsigned short* __restrict__ Wt,
                                            unsigned short* __restrict__ Wot) {
    int bid = blockIdx.x;
    int tid = threadIdx.x;
    if (bid < 4096) {  // cast: 1M float4
        int i = bid * 256 + tid;
        float4 v = *(const float4*)(x + (size_t)i * 4);
        unsigned short o[4] = {f2bf(v.x), f2bf(v.y), f2bf(v.z), f2bf(v.w)};
        *(unsigned long long*)(xb + (size_t)i * 4) = *(unsigned long long*)o;
        return;
    }
    bid -= 4096;
    const float* W; unsigned short* D; int K, N;
    if (bid < 512)       { W = Wq; D = Wt;                          K = 1024; N = 2048; }
    else if (bid < 768)  { bid -= 512;  W = Wk; D = Wt + (size_t)2048 * 1024; K = 1024; N = 1024; }
    else if (bid < 1024) { bid -= 768;  W = Wv; D = Wt + (size_t)3072 * 1024; K = 1024; N = 1024; }
    else                 { bid -= 1024; W = Wo; D = Wot;                      K = 2048; N = 1024; }
    __shared__ __attribute__((aligned(16))) unsigned short Ls[64 * 72];
    int ntiles = N >> 6;
    int kt = bid / ntiles, nt = bid - kt * ntiles;
    int k0 = kt * 64, n0 = nt * 64;
    for (int t = 0; t < 4; t++) {
        int idx = tid + t * 256;
        int r = idx >> 4, seg = idx & 15;
        float4 v = *(const float4*)(W + (size_t)(k0 + r) * N + n0 + seg * 4);
        int c = seg * 4;
        Ls[(c + 0) * 72 + r] = f2bf(v.x);
        Ls[(c + 1) * 72 + r] = f2bf(v.y);
        Ls[(c + 2) * 72 + r] = f2bf(v.z);
        Ls[(c + 3) * 72 + r] = f2bf(v.w);
    }
    __syncthreads();
    for (int t = 0; t < 2; t++) {
        int idx = tid + t * 256;
        int rr = idx >> 3, seg = idx & 7;
        uint4v v = *(const uint4v*)(Ls + rr * 72 + seg * 8);
        *(uint4v*)(D + (size_t)(n0 + rr) * K + k0 + seg * 8) = v;
    }
}

// ---------------- GEMM (QKV): C[M,N] = A[M,K](bf16) @ Bt[N,K]^T(bf16), BK=32, BN=128 --------
// Round-5 lesson: BN=64/BK=64 regressed this shape (2x blocks -> +50% panel traffic);
// this BN=128/BK=32 form is the measured best for the QKV projection.
template <int OUT_BF16, int BN>
__global__ __launch_bounds__(256) void gemm_bt(const unsigned short* __restrict__ A,
                                               const unsigned short* __restrict__ Bt,
                                               void* __restrict__ Cout,
                                               int M, int N, int K) {
    constexpr int MT = (BN == 128) ? 4 : 2;
    __shared__ __attribute__((aligned(16))) unsigned short As[2][128 * 32];
    __shared__ __attribute__((aligned(16))) unsigned short Bs[2][BN * 32];
    const int tid = threadIdx.x;
    const int lane = tid & 63;
    const int warp = tid >> 6;
    const int ln = lane & 15;
    const int quad = lane >> 4;
    const int wm = (BN == 128) ? (warp >> 1) : warp;
    const int wn = (BN == 128) ? (warp & 1) : 0;
    const int m0 = blockIdx.y * 128;
    const int n0 = blockIdx.x * BN;

    const int srow = lane >> 2;
    const int schunk = (lane & 3) ^ (srow & 3);
    const unsigned short* Ag = A + (size_t)(m0 + warp * 16 + srow) * K + schunk * 8;
    const unsigned short* Bg = Bt + (size_t)(n0 + warp * 16 + srow) * K + schunk * 8;

    f32x4 acc[MT][4];
#pragma unroll
    for (int i = 0; i < MT; i++)
#pragma unroll
        for (int j = 0; j < 4; j++) acc[i][j] = (f32x4){0.f, 0.f, 0.f, 0.f};

    auto stage = [&](int k0, int bi) {
        glds16(Ag + k0, As[bi] + warp * 16 * 32);
        glds16(Ag + (size_t)64 * K + k0, As[bi] + warp * 16 * 32 + 64 * 32);
        glds16(Bg + k0, Bs[bi] + warp * 16 * 32);
        if (BN == 128) glds16(Bg + (size_t)64 * K + k0, Bs[bi] + warp * 16 * 32 + 64 * 32);
    };

    const int rq = quad ^ (ln & 3);   // swizzled read chunk
    const int KI = K >> 5;
    stage(0, 0);
    for (int it = 0; it < KI; it++) {
        __syncthreads();            // drains my glds for buf it&1
        if (it + 1 < KI) stage((it + 1) << 5, (it + 1) & 1);
        const unsigned short* Ab = As[it & 1];
        const unsigned short* Bb = Bs[it & 1];
        short8 af[MT], bf[4];
#pragma unroll
        for (int mt = 0; mt < MT; mt++)
            af[mt] = *(const short8*)(Ab + (wm * (MT * 16) + mt * 16 + ln) * 32 + rq * 8);
#pragma unroll
        for (int nt = 0; nt < 4; nt++)
            bf[nt] = *(const short8*)(Bb + (wn * 64 + nt * 16 + ln) * 32 + rq * 8);
#pragma unroll
        for (int mt = 0; mt < MT; mt++)
#pragma unroll
            for (int nt = 0; nt < 4; nt++)
                acc[mt][nt] = __builtin_amdgcn_mfma_f32_16x16x32_bf16(bf[nt], af[mt], acc[mt][nt], 0, 0, 0);
    }
#pragma unroll
    for (int mt = 0; mt < MT; mt++) {
        int row = m0 + wm * (MT * 16) + mt * 16 + ln;
#pragma unroll
        for (int nt = 0; nt < 4; nt++) {
            int colb = n0 + wn * 64 + nt * 16 + quad * 4;
            if (OUT_BF16) {
                unsigned long long pk =
                    (unsigned long long)cvtpk(acc[mt][nt][0], acc[mt][nt][1]) |
                    ((unsigned long long)cvtpk(acc[mt][nt][2], acc[mt][nt][3]) << 32);
                *(unsigned long long*)((unsigned short*)Cout + (size_t)row * N + colb) = pk;
            } else {
                *(f32x4*)((float*)Cout + (size_t)row * N + colb) = acc[mt][nt];
            }
        }
    }
}

// ---------------- GEMM (O-proj): BM=128, BN=64, BK=64 -- round-2 measured win -------------
template <int OUT_BF16>
__global__ __launch_bounds__(256) void gemm_o(const unsigned short* __restrict__ A,
                                              const unsigned short* __restrict__ Bt,
                                              void* __restrict__ Cout,
                                              int M, int N, int K) {
    __shared__ __attribute__((aligned(16))) unsigned short As[2][128 * 64];  // 32 KB
    __shared__ __attribute__((aligned(16))) unsigned short Bs[2][64 * 64];   // 16 KB
    const int tid = threadIdx.x;
    const int lane = tid & 63;
    const int warp = tid >> 6;
    const int ln = lane & 15;
    const int quad = lane >> 4;
    const int m0 = blockIdx.y * 128;
    const int n0 = blockIdx.x * 64;

    const int srow = lane >> 3;            // 0..7
    const int schunk = (lane & 7) ^ srow;  // inverse-swizzled source chunk
    const unsigned short* Ag = A + (size_t)(m0 + warp * 32 + srow) * K + schunk * 8;
    const unsigned short* Bg = Bt + (size_t)(n0 + warp * 16 + srow) * K + schunk * 8;

    f32x4 acc[2][4];
#pragma unroll
    for (int i = 0; i < 2; i++)
#pragma unroll
        for (int j = 0; j < 4; j++) acc[i][j] = (f32x4){0.f, 0.f, 0.f, 0.f};

    auto stage = [&](int k0, int bi) {
#pragma unroll
        for (int g = 0; g < 4; g++)   // A rows warp*32 + g*8 + srow
            glds16(Ag + (size_t)(g * 8) * K + k0, As[bi] + (warp * 32 + g * 8) * 64);
#pragma unroll
        for (int g = 0; g < 2; g++)   // B rows warp*16 + g*8 + srow
            glds16(Bg + (size_t)(g * 8) * K + k0, Bs[bi] + (warp * 16 + g * 8) * 64);
    };

    const int KI = K >> 6;
    stage(0, 0);
    for (int it = 0; it < KI; it++) {
        __syncthreads();            // drains my glds for buf it&1
        if (it + 1 < KI) stage((it + 1) << 6, (it + 1) & 1);
        const unsigned short* Ab = As[it & 1];
        const unsigned short* Bb = Bs[it & 1];
#pragma unroll
        for (int ks = 0; ks < 2; ks++) {
            const int rc = ((ks << 2) + quad) ^ (ln & 7);
            short8 af[2], bf[4];
#pragma unroll
            for (int mt = 0; mt < 2; mt++)
                af[mt] = *(const short8*)(Ab + (warp * 32 + mt * 16 + ln) * 64 + rc * 8);
#pragma unroll
            for (int nt = 0; nt < 4; nt++)
                bf[nt] = *(const short8*)(Bb + (nt * 16 + ln) * 64 + rc * 8);
#pragma unroll
            for (int mt = 0; mt < 2; mt++)
#pragma unroll
                for (int nt = 0; nt < 4; nt++)
                    acc[mt][nt] = __builtin_amdgcn_mfma_f32_16x16x32_bf16(bf[nt], af[mt], acc[mt][nt], 0, 0, 0);
        }
    }
#pragma unroll
    for (int mt = 0; mt < 2; mt++) {
        int row = m0 + warp * 32 + mt * 16 + ln;
#pragma unroll
        for (int nt = 0; nt < 4; nt++) {
            int colb = n0 + nt * 16 + quad * 4;
            if (OUT_BF16) {
                unsigned long long pk =
                    (unsigned long long)cvtpk(acc[mt][nt][0], acc[mt][nt][1]) |
                    ((unsigned long long)cvtpk(acc[mt][nt][2], acc[mt][nt][3]) << 32);
                *(unsigned long long*)((unsigned short*)Cout + (size_t)row * N + colb) = pk;
            } else {
                *(f32x4*)((float*)Cout + (size_t)row * N + colb) = acc[mt][nt];
            }
        }
    }
}

// ---------------- fused norm_rope (blocks < 12288) + v_transpose (rest) ----------------
__global__ __launch_bounds__(256) void nrvt(const unsigned short* __restrict__ QKV,
                                            const float* __restrict__ qw,
                                            const float* __restrict__ kw,
                                            unsigned short* __restrict__ Q,
                                            unsigned short* __restrict__ Kb,
                                            unsigned short* __restrict__ Vt) {
    if (blockIdx.x < 12288) {
        const int tid = threadIdx.x;
        const int l5 = tid & 31;
        const int task = blockIdx.x * 8 + (tid >> 5);   // 98304 tasks
        const int tok = task / 24;
        const int slot = task - tok * 24;
        const int b = tok >> 11, t = tok & 2047;
        const float* w;
        unsigned short* dst;
        int col0;
        float sc;
        if (slot < 16) {
            col0 = slot * HD;
            dst = Q + ((size_t)(b * 16 + slot) * TSEQ + t) * HD;
            w = qw;
            sc = 0.12750580997495268f;  // (1/sqrt(128)) * log2(e) folded into Q
        } else {
            int hk = slot - 16;
            col0 = QOUT + hk * HD;
            dst = Kb + ((size_t)(b * 8 + hk) * TSEQ + t) * HD;
            w = kw;
            sc = 1.0f;
        }
        const unsigned short* row = QKV + (size_t)tok * 4096 + col0;
        unsigned long long pkin = *(const unsigned long long*)(row + l5 * 4);
        unsigned short us[4];
        *(unsigned long long*)us = pkin;
        float e[4];
        float ss = 0.f;
#pragma unroll
        for (int k = 0; k < 4; k++) { e[k] = bf2f(us[k]); ss += e[k] * e[k]; }
#pragma unroll
        for (int off = 1; off < 32; off <<= 1) ss += __shfl_xor(ss, off);
        float rr = rsqrtf(ss * (1.0f / 128.0f) + 1e-6f);
        float4 wv = *(const float4*)(w + l5 * 4);
        float n[4] = { e[0] * rr * wv.x, e[1] * rr * wv.y, e[2] * rr * wv.z, e[3] * rr * wv.w };
        float np[4];
#pragma unroll
        for (int k = 0; k < 4; k++) np[k] = __shfl_xor(n[k], 16);
        const float tf = (float)t;
        const int fb = (l5 & 15) * 4;      // freq index base = d % 64
        const bool hi = (l5 >= 16);
        unsigned short outs[4];
#pragma unroll
        for (int k = 0; k < 4; k++) {
            float invf = __builtin_exp2f(-(float)(fb + k) * 0.20762050593045951f);
            float sf, cf;
            __sincosf(tf * invf, &sf, &cf);
            float o = hi ? (n[k] * cf + np[k] * sf) : (n[k] * cf - np[k] * sf);
            outs[k] = f2bf(o * sc);
        }
        *(unsigned long long*)(dst + l5 * 4) = *(unsigned long long*)outs;
        return;
    }
    // v_transpose
    __shared__ __attribute__((aligned(16))) unsigned short Ls[128 * 72];
    int bid = blockIdx.x - 12288;
    int tt = bid & 31, hk = (bid >> 5) & 7, b = bid >> 8;
    int t0 = tt * 64;
    int tid = threadIdx.x;
    const unsigned short* base = QKV + (size_t)(b * 2048 + t0) * 4096 + 3072 + hk * 128;
    for (int i = 0; i < 4; i++) {
        int idx = tid + i * 256;
        int r = idx >> 4, seg = idx & 15;
        uint4v v = *(const uint4v*)(base + (size_t)r * 4096 + seg * 8);
        unsigned short* pv = (unsigned short*)&v;
        int d = seg * 8;
        for (int jj = 0; jj < 8; jj++) Ls[(d + jj) * 72 + r] = pv[jj];
    }
    __syncthreads();
    unsigned short* out = Vt + (size_t)(b * 8 + hk) * 128 * 2048;
    for (int i = 0; i < 4; i++) {
        int idx = tid + i * 256;
        int d = idx >> 3, seg = idx & 7;
        uint4v v = *(const uint4v*)(Ls + d * 72 + seg * 8);
        *(uint4v*)(out + (size_t)d * 2048 + t0 + seg * 8) = v;
    }
}

// ---------------- flash attention v13: v11 + parity-complement p remap ---------------------
// v12 post-mortem: (512,8) VGPR-starved the kernel (VGPR 32, 150MB scratch writes, 4x slow).
// Reverted to v11 (KVBLK=64, 64KB LDS, 2 blocks/CU, permlane P crossbar, 0 conflicts).
// v13's single change: p = (px&1) ? 15-(px>>1) : (px>>1). The grid (512 blocks) is exactly
// co-resident (2/CU x 256 CU), so wall = slowest CU's load and adjacent dispatch ids (2c,
// 2c+1) are the likely CU pair. Old mapping gave them p=2i,2i+1 -> CU loads 35T..63T (wall
// 63T). New mapping gives (i, 15-i) -> every CU 49T. If pairing is instead c/c+256 (round-2
// evidence killed that fix), this remap is exactly neutral (same parity -> same p).
__global__ __launch_bounds__(512, 4) void attn(const unsigned short* __restrict__ Q,
                                               const unsigned short* __restrict__ Kg,
                                               const unsigned short* __restrict__ Vt,
                                               unsigned short* __restrict__ Og) {
    __shared__ __attribute__((aligned(16))) unsigned short Ks[2][64 * 128];  // swizzled (kv, d)
    __shared__ __attribute__((aligned(16))) unsigned short Vs[2][128 * 64];  // swizzled (d, kv)
    const int px = blockIdx.x;
    const int p = (px & 1) ? (15 - (px >> 1)) : (px >> 1);
    const int bh = blockIdx.y;
    const int b = bh >> 4, h = bh & 15, hk = h >> 1;
    const int tid = threadIdx.x;
    const int w = tid >> 6, lane = tid & 63, ln = lane & 15, quad = lane >> 4;
    const int sg = w >> 2;                    // strip group: 0 -> tile p, 1 -> tile 31-p
    const int wi = w & 3;
    const int tile = sg ? (31 - p) : p;
    const int jdiag = tile;                   // kv-tile index where the causal diagonal falls
    const int qrow0 = tile * 64 + wi * 16;    // this wave's 16 q-rows

    const unsigned short* Kbase = Kg + (size_t)(b * 8 + hk) * TSEQ * HD;
    const unsigned short* Vbase = Vt + (size_t)(b * 8 + hk) * HD * TSEQ;
    const unsigned short* Qh = Q + (size_t)(b * 16 + h) * TSEQ * HD;

    short8 qf[4];
#pragma unroll
    for (int kt = 0; kt < 4; kt++)
        qf[kt] = *(const short8*)(Qh + (size_t)(qrow0 + ln) * HD + kt * 32 + quad * 8);

    f32x4 o[8];
    f32x4 lac = (f32x4){0.f, 0.f, 0.f, 0.f};
#pragma unroll
    for (int ot = 0; ot < 8; ot++) o[ot] = (f32x4){0.f, 0.f, 0.f, 0.f};
    float m_ = -1e30f;

    const int kr = lane >> 4;
    const int kc = lane & 15;
    const int vr = lane >> 3;
    const int vc = lane & 7;

    // staging split across 8 warps: warp w stages K rows [w*8, w*8+8) and V d-rows
    // [w*16, w*16+16) -- 4 glds16 per warp per tile.
    auto stage_kv = [&](int jt, int bi) {
        const int j0s = jt * 64;
        unsigned short* KsB = Ks[bi];
        unsigned short* VsB = Vs[bi];
#pragma unroll
        for (int c = 0; c < 2; c++) {   // K: LDS[r][c] = K[r][c ^ (r&15)]
            int row = w * 8 + c * 4 + kr;
            glds16(Kbase + (size_t)(j0s + row) * HD + ((kc ^ (row & 15)) * 8),
                   KsB + (w * 8 + c * 4) * 128);
        }
#pragma unroll
        for (int c = 0; c < 2; c++) {   // V^T: LDS[d][c] = V[d][c ^ (d&7)]
            int d = w * 16 + c * 8 + vr;
            glds16(Vbase + (size_t)d * TSEQ + j0s + ((vc ^ (d & 7)) * 8),
                   VsB + (w * 16 + c * 8) * 64);
        }
    };

    // bf16 1.0 fragment for row-sum MFMA (B = all-ones 16x32)
    short8 ones8;
#pragma unroll
    for (int i = 0; i < 8; i++) ones8[i] = (short)0x3F80;

    const int nT = 32 - p;
    stage_kv(0, 0);
    for (int j = 0; j < nT; j++) {
        __syncthreads();                 // drains my glds for buf j&1 (prev iter's prefetch)
        if (j + 1 < nT) stage_kv(j + 1, (j + 1) & 1);
        const unsigned short* KsC = Ks[j & 1];
        const unsigned short* VsC = Vs[j & 1];
        const bool act = sg ? true : (j <= jdiag);
        if (act) {
            // ---- QK^T (Q pre-scaled: s is in exp2 domain) ----
            f32x4 s[4];
#pragma unroll
            for (int kb = 0; kb < 4; kb++) s[kb] = (f32x4){0.f, 0.f, 0.f, 0.f};
            __builtin_amdgcn_s_setprio(1);
#pragma unroll
            for (int kt = 0; kt < 4; kt++) {
                short8 kf[4];
#pragma unroll
                for (int kb = 0; kb < 4; kb++)
                    kf[kb] = *(const short8*)(KsC + (kb * 16 + ln) * 128 + (((kt * 4 + quad) ^ ln) * 8));
#pragma unroll
                for (int kb = 0; kb < 4; kb++)
                    s[kb] = __builtin_amdgcn_mfma_f32_16x16x32_bf16(kf[kb], qf[kt], s[kb], 0, 0, 0);
            }
            __builtin_amdgcn_s_setprio(0);
            // ---- softmax: defer-max (THR=8), shuffle-free common path ----
            float mk[4];
            if (j == jdiag) {
                const int qloc = wi * 16 + ln;
#pragma unroll
                for (int kb = 0; kb < 4; kb++) {
#pragma unroll
                    for (int r = 0; r < 4; r++) {
                        int kvloc = kb * 16 + quad * 4 + r;
                        if (kvloc > qloc) s[kb][r] = -1e30f;
                    }
                    mk[kb] = fmaxf(fmaxf(s[kb][0], s[kb][1]), fmaxf(s[kb][2], s[kb][3]));
                }
            } else {
#pragma unroll
                for (int kb = 0; kb < 4; kb++)
                    mk[kb] = fmaxf(fmaxf(s[kb][0], s[kb][1]), fmaxf(s[kb][2], s[kb][3]));
            }
            float mx = fmaxf(fmaxf(mk[0], mk[1]), fmaxf(mk[2], mk[3]));
            float mn = m_;
            bool needR = false;
            float alpha = 1.f;
            if (!__all(mx <= mn + 8.0f)) {
                mx = fmaxf(mx, __shfl_xor(mx, 16));
                mx = fmaxf(mx, __shfl_xor(mx, 32));
                mn = fmaxf(m_, mx);
                alpha = __builtin_exp2f(m_ - mn);
                m_ = mn;
                needR = true;
            }
            // ---- P -> bf16 packed, then VALU quad-crossbar (no LDS) ----
            unsigned int u[8];
#pragma unroll
            for (int kb = 0; kb < 4; kb++) {
                float p0 = __builtin_exp2f(s[kb][0] - mn);
                float p1 = __builtin_exp2f(s[kb][1] - mn);
                float p2 = __builtin_exp2f(s[kb][2] - mn);
                float p3 = __builtin_exp2f(s[kb][3] - mn);
                u[kb * 2 + 0] = cvtpk(p0, p1);   // kv = 16kb + 4*quad + {0,1}, q = ln
                u[kb * 2 + 1] = cvtpk(p2, p3);   // kv = 16kb + 4*quad + {2,3}
            }
            pl32(u[0], u[2]); pl16(u[0], u[2]);   // -> pf0 t0, t2
            pl32(u[1], u[3]); pl16(u[1], u[3]);   // -> pf0 t1, t3
            pl32(u[4], u[6]); pl16(u[4], u[6]);   // -> pf1 t0, t2
            pl32(u[5], u[7]); pl16(u[5], u[7]);   // -> pf1 t1, t3
            union { unsigned int uu[4]; short8 s8; } P0, P1;
            P0.uu[0] = u[0]; P0.uu[1] = u[1]; P0.uu[2] = u[2]; P0.uu[3] = u[3];
            P1.uu[0] = u[4]; P1.uu[1] = u[5]; P1.uu[2] = u[6]; P1.uu[3] = u[7];
            short8 pf0 = P0.s8;   // P[kv = 8*quad + {0..7}][q = ln]
            short8 pf1 = P1.s8;   // P[kv = 32 + 8*quad + {0..7}][q = ln]
            // ---- rescale O and l (uniform branch, rare after first tile) ----
            if (needR) {
#pragma unroll
                for (int ot = 0; ot < 8; ot++)
#pragma unroll
                    for (int r = 0; r < 4; r++) o[ot][r] *= alpha;
#pragma unroll
                for (int r = 0; r < 4; r++) lac[r] *= alpha;
            }
            // ---- PV + row-sum; operand-swapped (O: col=q=ln, rows=d) ----
            __builtin_amdgcn_s_setprio(1);
            lac = __builtin_amdgcn_mfma_f32_16x16x32_bf16(ones8, pf0, lac, 0, 0, 0);
            lac = __builtin_amdgcn_mfma_f32_16x16x32_bf16(ones8, pf1, lac, 0, 0, 0);
#pragma unroll
            for (int ot = 0; ot < 8; ot++) {
                short8 vf0 = *(const short8*)(VsC + (ot * 16 + ln) * 64 + ((quad ^ (ln & 7)) * 8));
                short8 vf1 = *(const short8*)(VsC + (ot * 16 + ln) * 64 + (((4 + quad) ^ (ln & 7)) * 8));
                o[ot] = __builtin_amdgcn_mfma_f32_16x16x32_bf16(vf0, pf0, o[ot], 0, 0, 0);
                o[ot] = __builtin_amdgcn_mfma_f32_16x16x32_bf16(vf1, pf1, o[ot], 0, 0, 0);
            }
            __builtin_amdgcn_s_setprio(0);
        }
    }
    // epilogue: lane has q = qrow0+ln; regs are 4 consecutive d -> 8B stores
    float inv = 1.0f / lac[0];
    size_t rowoff = ((size_t)(b * TSEQ + qrow0 + ln)) * QOUT + h * 128 + quad * 4;
#pragma unroll
    for (int ot = 0; ot < 8; ot++) {
        unsigned long long pk =
            (unsigned long long)cvtpk(o[ot][0] * inv, o[ot][1] * inv) |
            ((unsigned long long)cvtpk(o[ot][2] * inv, o[ot][3] * inv) << 32);
        *(unsigned long long*)(Og + rowoff + ot * 16) = pk;
    }
}

extern "C" void kernel_launch(void* const* d_in, const int* in_sizes, int n_in,
                              void* d_out, int out_size, void* d_ws, size_t ws_size,
                              hipStream_t stream) {
    (void)in_sizes; (void)n_in; (void)out_size;
    const float* x  = (const float*)d_in[0];
    const float* Wq = (const float*)d_in[1];
    const float* Wk = (const float*)d_in[2];
    const float* Wv = (const float*)d_in[3];
    const float* Wo = (const float*)d_in[4];
    const float* qw = (const float*)d_in[5];
    const float* kw = (const float*)d_in[6];

    char* ws = (char*)d_ws;
    const size_t MB = 1024 * 1024;
    unsigned short* Wt   = (unsigned short*)(ws);            // 8 MB
    unsigned short* Wot  = (unsigned short*)(ws + 8 * MB);   // 4 MB
    unsigned short* QKVb = (unsigned short*)(ws + 12 * MB);  // 32 MB (bf16)
    unsigned short* xb   = (unsigned short*)(ws + 44 * MB);  // 8 MB
    unsigned short* Qb   = (unsigned short*)(ws + 52 * MB);  // 16 MB
    unsigned short* Kb   = (unsigned short*)(ws + 68 * MB);  // 8 MB
    unsigned short* Vtb  = (unsigned short*)(ws + 76 * MB);  // 8 MB
    unsigned short* Ob   = (unsigned short*)(ws + 84 * MB);  // 16 MB
    if (ws_size < 100 * MB) return;

    prep<<<dim3(5632), 256, 0, stream>>>(x, Wq, Wk, Wv, Wo, xb, Wt, Wot);
    gemm_bt<1, 128><<<dim3(32, 32), 256, 0, stream>>>(xb, Wt, QKVb, 4096, 4096, 1024);
    nrvt<<<dim3(12800), 256, 0, stream>>>(QKVb, qw, kw, Qb, Kb, Vtb);
    attn<<<dim3(16, 32), 512, 0, stream>>>(Qb, Kb, Vtb, Ob);
    gemm_o<0><<<dim3(16, 32), 256, 0, stream>>>(Ob, Wot, (float*)d_out, 4096, 1024, 2048);
}

// Round 9
// 247.693 us; speedup vs baseline: 1.7884x; 1.0018x over previous
//
#include <hip/hip_runtime.h>
#include <math.h>

typedef __attribute__((ext_vector_type(8))) short short8;
typedef __attribute__((ext_vector_type(4))) float f32x4;
typedef __attribute__((ext_vector_type(4))) unsigned int uint4v;

#define HIDDEN 1024
#define QOUT 2048
#define KVOUT 1024
#define HD 128
#define TSEQ 2048

__device__ __forceinline__ float bf2f(unsigned short h) {
    union { unsigned int u; float f; } x; x.u = ((unsigned int)h) << 16; return x.f;
}
__device__ __forceinline__ unsigned short f2bf(float f) {
    union { float f; unsigned int u; } x; x.f = f;
    unsigned int r = (x.u + 0x7fffu + ((x.u >> 16) & 1u)) >> 16;
    return (unsigned short)r;
}
// HW packed f32->bf16 (RNE, same semantics as f2bf pair) -- 1 VALU op per 2 values
__device__ __forceinline__ unsigned int cvtpk(float lo, float hi) {
    unsigned int r;
    asm("v_cvt_pk_bf16_f32 %0, %1, %2" : "=v"(r) : "v"(lo), "v"(hi));
    return r;
}
// gfx950 cross-lane swaps (VALU pipe -- no LDS):
__device__ __forceinline__ void pl32(unsigned int& a, unsigned int& b) {
    asm("v_permlane32_swap_b32 %0, %1" : "+v"(a), "+v"(b));
}
__device__ __forceinline__ void pl16(unsigned int& a, unsigned int& b) {
    asm("v_permlane16_swap_b32 %0, %1" : "+v"(a), "+v"(b));
}

// async global->LDS, 16B per lane; dest = wave-uniform base + lane*16
__device__ __forceinline__ void glds16(const unsigned short* g, unsigned short* l) {
    __builtin_amdgcn_global_load_lds(
        (const __attribute__((address_space(1))) unsigned int*)g,
        (__attribute__((address_space(3))) unsigned int*)l, 16, 0, 0);
}

// ---------------- prep: cast x->bf16  +  4 weight transposes (fp32 KxN -> bf16 NxK) ---------
__global__ __launch_bounds__(256) void prep(const float* __restrict__ x,
                                            const float* __restrict__ Wq,
                                            const float* __restrict__ Wk,
                                            const float* __restrict__ Wv,
                                            const float* __restrict__ Wo,
                                            unsigned short* __restrict__ xb,
                                            unsigned short* __restrict__ Wt,
                                            unsigned short* __restrict__ Wot) {
    int bid = blockIdx.x;
    int tid = threadIdx.x;
    if (bid < 4096) {  // cast: 1M float4
        int i = bid * 256 + tid;
        float4 v = *(const float4*)(x + (size_t)i * 4);
        unsigned short o[4] = {f2bf(v.x), f2bf(v.y), f2bf(v.z), f2bf(v.w)};
        *(unsigned long long*)(xb + (size_t)i * 4) = *(unsigned long long*)o;
        return;
    }
    bid -= 4096;
    const float* W; unsigned short* D; int K, N;
    if (bid < 512)       { W = Wq; D = Wt;                          K = 1024; N = 2048; }
    else if (bid < 768)  { bid -= 512;  W = Wk; D = Wt + (size_t)2048 * 1024; K = 1024; N = 1024; }
    else if (bid < 1024) { bid -= 768;  W = Wv; D = Wt + (size_t)3072 * 1024; K = 1024; N = 1024; }
    else                 { bid -= 1024; W = Wo; D = Wot;                      K = 2048; N = 1024; }
    __shared__ __attribute__((aligned(16))) unsigned short Ls[64 * 72];
    int ntiles = N >> 6;
    int kt = bid / ntiles, nt = bid - kt * ntiles;
    int k0 = kt * 64, n0 = nt * 64;
    for (int t = 0; t < 4; t++) {
        int idx = tid + t * 256;
        int r = idx >> 4, seg = idx & 15;
        float4 v = *(const float4*)(W + (size_t)(k0 + r) * N + n0 + seg * 4);
        int c = seg * 4;
        Ls[(c + 0) * 72 + r] = f2bf(v.x);
        Ls[(c + 1) * 72 + r] = f2bf(v.y);
        Ls[(c + 2) * 72 + r] = f2bf(v.z);
        Ls[(c + 3) * 72 + r] = f2bf(v.w);
    }
    __syncthreads();
    for (int t = 0; t < 2; t++) {
        int idx = tid + t * 256;
        int rr = idx >> 3, seg = idx & 7;
        uint4v v = *(const uint4v*)(Ls + rr * 72 + seg * 8);
        *(uint4v*)(D + (size_t)(n0 + rr) * K + k0 + seg * 8) = v;
    }
}

// ---------------- GEMM (QKV): 256x256 tile, BK=64, 8-phase counted-vmcnt pipeline ----------
// Port of the 8-phase template (T3+T4): iteration = 2 K-steps = 8 phases; per phase
// {ds_read quadrant subtile -> issue ONE half-tile prefetch (2 glds16/wave) -> s_barrier ->
// setprio(1) 16 MFMA setprio(0) -> [vmcnt ckpt at ph4/ph8] -> s_barrier}. Counted vmcnt(4)
// keeps 2 half-tiles in flight across barriers (never drains to 0 in the main loop).
// LDS 128KB = 2 bufs x 4 halves (Ah0,Ah1,Bh0,Bh1) x 128x64 bf16. 8 waves (2M x 4N),
// per-wave C = 128x64 = acc[2][2][4][2] f32x4. 8-chunk XOR swizzle (proven in gemm_o).
// Issue schedule ph1..8 = {B1.A0,B1.A1,B0.B0',B0.B1',B0.A0',B0.A1',B1.B0',B1.B1'} -- each
// target region's last LDS read is >=1 barrier earlier (WAR-safe). Last iter: vmcnt(0).
__global__ __launch_bounds__(512, 2) void gemm8(const unsigned short* __restrict__ A,
                                                const unsigned short* __restrict__ Bt,
                                                unsigned short* __restrict__ Cout,
                                                int M, int N, int K) {
    (void)M;
    __shared__ __attribute__((aligned(16))) unsigned short L[2][4][128 * 64];  // 128 KB
    const int tid = threadIdx.x;
    const int lane = tid & 63;
    const int w = tid >> 6;
    const int ln = lane & 15;
    const int quad = lane >> 4;
    const int wm2 = w >> 2;       // 0..1 : M half
    const int wn4 = w & 3;        // 0..3 : N quarter
    const int m0 = blockIdx.y * 256;
    const int n0 = blockIdx.x * 256;

    const int srow8 = lane >> 3;             // 0..7
    const int schunk = (lane & 7) ^ srow8;   // inverse-swizzled source chunk
    const int KS = K >> 6;                   // number of BK=64 K-steps
    const int NJ = K >> 7;                   // iterations (2 K-steps each)

    f32x4 acc[2][2][4][2];
#pragma unroll
    for (int a = 0; a < 2; a++)
#pragma unroll
        for (int b = 0; b < 2; b++)
#pragma unroll
            for (int c = 0; c < 4; c++)
#pragma unroll
                for (int d = 0; d < 2; d++) acc[a][b][c][d] = (f32x4){0.f, 0.f, 0.f, 0.f};

    // issue one half-tile (16KB collectively; this wave's 2KB = 2 glds16) for K-step ks_
    auto issue = [&](int ks_, int half) {
        if (ks_ >= KS) return;
        const unsigned short* src = (half < 2) ? A : Bt;
        const int rbase = ((half < 2) ? m0 : n0) + (half & 1) * 128;
        unsigned short* dst = &L[ks_ & 1][half][0];
#pragma unroll
        for (int g = 0; g < 2; g++) {
            glds16(src + (size_t)(rbase + w * 16 + g * 8 + srow8) * K + ks_ * 64 + schunk * 8,
                   dst + (w * 16 + g * 8) * 64);
        }
    };

    short8 af[4][2];       // A frags: rt x ks (current rh)
    short8 bfr[2][2][2];   // B frags: ch x ct x ks (persist across the 4 phases)

#define RD_A(LB, RH)                                                                     \
    _Pragma("unroll") for (int rt = 0; rt < 4; rt++)                                     \
        _Pragma("unroll") for (int ks = 0; ks < 2; ks++)                                 \
            af[rt][ks] = *(const short8*)((LB) + ((RH)*64 + rt * 16 + ln) * 64 +         \
                                          ((((ks << 2) + quad) ^ (ln & 7)) * 8));

#define RD_B(LB, CH)                                                                     \
    _Pragma("unroll") for (int ct = 0; ct < 2; ct++)                                     \
        _Pragma("unroll") for (int ks = 0; ks < 2; ks++)                                 \
            bfr[CH][ct][ks] = *(const short8*)((LB) + ((wn4 & 1) * 64 + (CH)*32 +        \
                                               ct * 16 + ln) * 64 +                      \
                                               ((((ks << 2) + quad) ^ (ln & 7)) * 8));

#define MMA_Q(RH, CH)                                                                    \
    __builtin_amdgcn_s_setprio(1);                                                       \
    _Pragma("unroll") for (int ks = 0; ks < 2; ks++)                                     \
        _Pragma("unroll") for (int rt = 0; rt < 4; rt++)                                 \
            _Pragma("unroll") for (int ct = 0; ct < 2; ct++)                             \
                acc[RH][CH][rt][ct] = __builtin_amdgcn_mfma_f32_16x16x32_bf16(           \
                    bfr[CH][ct][ks], af[rt][ks], acc[RH][CH][rt][ct], 0, 0, 0);          \
    __builtin_amdgcn_s_setprio(0);

#define BAR() __builtin_amdgcn_s_barrier()

    // prologue: K-step0 all 4 halves + K-step1 B halves (12 loads/wave); need first 8 -> vmcnt(4)
    issue(0, 0); issue(0, 1); issue(0, 2); issue(0, 3);
    issue(1, 2); issue(1, 3);
    asm volatile("s_waitcnt vmcnt(4)" ::: "memory");
    BAR();

    for (int j = 0; j < NJ; j++) {
        const bool last = (j == NJ - 1);
        const unsigned short* A0 = &L[0][wm2][0];
        const unsigned short* B0 = &L[0][2 + (wn4 >> 1)][0];
        const unsigned short* A1 = &L[1][wm2][0];
        const unsigned short* B1 = &L[1][2 + (wn4 >> 1)][0];
        const int k1 = 2 * j + 1, k2 = 2 * j + 2, k3 = 2 * j + 3;
        // ---------- buf0 half-iteration (K-step 2j) ----------
        // ph1
        RD_A(A0, 0); RD_B(B0, 0);
        issue(k1, 0);
        BAR(); MMA_Q(0, 0); BAR();
        // ph2
        RD_B(B0, 1);
        issue(k1, 1);
        BAR(); MMA_Q(0, 1); BAR();
        // ph3
        RD_A(A0, 1);
        issue(k2, 2);
        BAR(); MMA_Q(1, 1); BAR();
        // ph4 (reuses af rh1 + bfr ch0)
        issue(k2, 3);
        BAR(); MMA_Q(1, 0);
        if (last) { asm volatile("s_waitcnt vmcnt(0)" ::: "memory"); }
        else      { asm volatile("s_waitcnt vmcnt(4)" ::: "memory"); }
        BAR();
        // ---------- buf1 half-iteration (K-step 2j+1) ----------
        // ph5
        RD_A(A1, 0); RD_B(B1, 0);
        issue(k2, 0);
        BAR(); MMA_Q(0, 0); BAR();
        // ph6
        RD_B(B1, 1);
        issue(k2, 1);
        BAR(); MMA_Q(0, 1); BAR();
        // ph7
        RD_A(A1, 1);
        issue(k3, 2);
        BAR(); MMA_Q(1, 1); BAR();
        // ph8
        issue(k3, 3);
        BAR(); MMA_Q(1, 0);
        if (!last) { asm volatile("s_waitcnt vmcnt(4)" ::: "memory"); }
        BAR();
    }

    // epilogue: C bf16, 8B stores
#pragma unroll
    for (int rh = 0; rh < 2; rh++)
#pragma unroll
        for (int rt = 0; rt < 4; rt++) {
            int row = m0 + wm2 * 128 + rh * 64 + rt * 16 + ln;
#pragma unroll
            for (int ch = 0; ch < 2; ch++)
#pragma unroll
                for (int ct = 0; ct < 2; ct++) {
                    int colb = n0 + wn4 * 64 + ch * 32 + ct * 16 + quad * 4;
                    f32x4 v = acc[rh][ch][rt][ct];
                    unsigned long long pk =
                        (unsigned long long)cvtpk(v[0], v[1]) |
                        ((unsigned long long)cvtpk(v[2], v[3]) << 32);
                    *(unsigned long long*)(Cout + (size_t)row * N + colb) = pk;
                }
        }
#undef RD_A
#undef RD_B
#undef MMA_Q
#undef BAR
}

// ---------------- GEMM (O-proj): BM=128, BN=64, BK=64 -- round-2 measured win -------------
template <int OUT_BF16>
__global__ __launch_bounds__(256) void gemm_o(const unsigned short* __restrict__ A,
                                              const unsigned short* __restrict__ Bt,
                                              void* __restrict__ Cout,
                                              int M, int N, int K) {
    __shared__ __attribute__((aligned(16))) unsigned short As[2][128 * 64];  // 32 KB
    __shared__ __attribute__((aligned(16))) unsigned short Bs[2][64 * 64];   // 16 KB
    const int tid = threadIdx.x;
    const int lane = tid & 63;
    const int warp = tid >> 6;
    const int ln = lane & 15;
    const int quad = lane >> 4;
    const int m0 = blockIdx.y * 128;
    const int n0 = blockIdx.x * 64;

    const int srow = lane >> 3;            // 0..7
    const int schunk = (lane & 7) ^ srow;  // inverse-swizzled source chunk
    const unsigned short* Ag = A + (size_t)(m0 + warp * 32 + srow) * K + schunk * 8;
    const unsigned short* Bg = Bt + (size_t)(n0 + warp * 16 + srow) * K + schunk * 8;

    f32x4 acc[2][4];
#pragma unroll
    for (int i = 0; i < 2; i++)
#pragma unroll
        for (int j = 0; j < 4; j++) acc[i][j] = (f32x4){0.f, 0.f, 0.f, 0.f};

    auto stage = [&](int k0, int bi) {
#pragma unroll
        for (int g = 0; g < 4; g++)   // A rows warp*32 + g*8 + srow
            glds16(Ag + (size_t)(g * 8) * K + k0, As[bi] + (warp * 32 + g * 8) * 64);
#pragma unroll
        for (int g = 0; g < 2; g++)   // B rows warp*16 + g*8 + srow
            glds16(Bg + (size_t)(g * 8) * K + k0, Bs[bi] + (warp * 16 + g * 8) * 64);
    };

    const int KI = K >> 6;
    stage(0, 0);
    for (int it = 0; it < KI; it++) {
        __syncthreads();            // drains my glds for buf it&1
        if (it + 1 < KI) stage((it + 1) << 6, (it + 1) & 1);
        const unsigned short* Ab = As[it & 1];
        const unsigned short* Bb = Bs[it & 1];
#pragma unroll
        for (int ks = 0; ks < 2; ks++) {
            const int rc = ((ks << 2) + quad) ^ (ln & 7);
            short8 af[2], bf[4];
#pragma unroll
            for (int mt = 0; mt < 2; mt++)
                af[mt] = *(const short8*)(Ab + (warp * 32 + mt * 16 + ln) * 64 + rc * 8);
#pragma unroll
            for (int nt = 0; nt < 4; nt++)
                bf[nt] = *(const short8*)(Bb + (nt * 16 + ln) * 64 + rc * 8);
#pragma unroll
            for (int mt = 0; mt < 2; mt++)
#pragma unroll
                for (int nt = 0; nt < 4; nt++)
                    acc[mt][nt] = __builtin_amdgcn_mfma_f32_16x16x32_bf16(bf[nt], af[mt], acc[mt][nt], 0, 0, 0);
        }
    }
#pragma unroll
    for (int mt = 0; mt < 2; mt++) {
        int row = m0 + warp * 32 + mt * 16 + ln;
#pragma unroll
        for (int nt = 0; nt < 4; nt++) {
            int colb = n0 + nt * 16 + quad * 4;
            if (OUT_BF16) {
                unsigned long long pk =
                    (unsigned long long)cvtpk(acc[mt][nt][0], acc[mt][nt][1]) |
                    ((unsigned long long)cvtpk(acc[mt][nt][2], acc[mt][nt][3]) << 32);
                *(unsigned long long*)((unsigned short*)Cout + (size_t)row * N + colb) = pk;
            } else {
                *(f32x4*)((float*)Cout + (size_t)row * N + colb) = acc[mt][nt];
            }
        }
    }
}

// ---------------- fused norm_rope (blocks < 12288) + v_transpose (rest) ----------------
__global__ __launch_bounds__(256) void nrvt(const unsigned short* __restrict__ QKV,
                                            const float* __restrict__ qw,
                                            const float* __restrict__ kw,
                                            unsigned short* __restrict__ Q,
                                            unsigned short* __restrict__ Kb,
                                            unsigned short* __restrict__ Vt) {
    if (blockIdx.x < 12288) {
        const int tid = threadIdx.x;
        const int l5 = tid & 31;
        const int task = blockIdx.x * 8 + (tid >> 5);   // 98304 tasks
        const int tok = task / 24;
        const int slot = task - tok * 24;
        const int b = tok >> 11, t = tok & 2047;
        const float* w;
        unsigned short* dst;
        int col0;
        float sc;
        if (slot < 16) {
            col0 = slot * HD;
            dst = Q + ((size_t)(b * 16 + slot) * TSEQ + t) * HD;
            w = qw;
            sc = 0.12750580997495268f;  // (1/sqrt(128)) * log2(e) folded into Q
        } else {
            int hk = slot - 16;
            col0 = QOUT + hk * HD;
            dst = Kb + ((size_t)(b * 8 + hk) * TSEQ + t) * HD;
            w = kw;
            sc = 1.0f;
        }
        const unsigned short* row = QKV + (size_t)tok * 4096 + col0;
        unsigned long long pkin = *(const unsigned long long*)(row + l5 * 4);
        unsigned short us[4];
        *(unsigned long long*)us = pkin;
        float e[4];
        float ss = 0.f;
#pragma unroll
        for (int k = 0; k < 4; k++) { e[k] = bf2f(us[k]); ss += e[k] * e[k]; }
#pragma unroll
        for (int off = 1; off < 32; off <<= 1) ss += __shfl_xor(ss, off);
        float rr = rsqrtf(ss * (1.0f / 128.0f) + 1e-6f);
        float4 wv = *(const float4*)(w + l5 * 4);
        float n[4] = { e[0] * rr * wv.x, e[1] * rr * wv.y, e[2] * rr * wv.z, e[3] * rr * wv.w };
        float np[4];
#pragma unroll
        for (int k = 0; k < 4; k++) np[k] = __shfl_xor(n[k], 16);
        const float tf = (float)t;
        const int fb = (l5 & 15) * 4;      // freq index base = d % 64
        const bool hi = (l5 >= 16);
        unsigned short outs[4];
#pragma unroll
        for (int k = 0; k < 4; k++) {
            float invf = __builtin_exp2f(-(float)(fb + k) * 0.20762050593045951f);
            float sf, cf;
            __sincosf(tf * invf, &sf, &cf);
            float o = hi ? (n[k] * cf + np[k] * sf) : (n[k] * cf - np[k] * sf);
            outs[k] = f2bf(o * sc);
        }
        *(unsigned long long*)(dst + l5 * 4) = *(unsigned long long*)outs;
        return;
    }
    // v_transpose
    __shared__ __attribute__((aligned(16))) unsigned short Ls[128 * 72];
    int bid = blockIdx.x - 12288;
    int tt = bid & 31, hk = (bid >> 5) & 7, b = bid >> 8;
    int t0 = tt * 64;
    int tid = threadIdx.x;
    const unsigned short* base = QKV + (size_t)(b * 2048 + t0) * 4096 + 3072 + hk * 128;
    for (int i = 0; i < 4; i++) {
        int idx = tid + i * 256;
        int r = idx >> 4, seg = idx & 15;
        uint4v v = *(const uint4v*)(base + (size_t)r * 4096 + seg * 8);
        unsigned short* pv = (unsigned short*)&v;
        int d = seg * 8;
        for (int jj = 0; jj < 8; jj++) Ls[(d + jj) * 72 + r] = pv[jj];
    }
    __syncthreads();
    unsigned short* out = Vt + (size_t)(b * 8 + hk) * 128 * 2048;
    for (int i = 0; i < 4; i++) {
        int idx = tid + i * 256;
        int d = idx >> 3, seg = idx & 7;
        uint4v v = *(const uint4v*)(Ls + d * 72 + seg * 8);
        *(uint4v*)(out + (size_t)d * 2048 + t0 + seg * 8) = v;
    }
}

// ---------------- flash attention v13 (round-8 best: 69us, FETCH-friendly remap) -----------
__global__ __launch_bounds__(512, 4) void attn(const unsigned short* __restrict__ Q,
                                               const unsigned short* __restrict__ Kg,
                                               const unsigned short* __restrict__ Vt,
                                               unsigned short* __restrict__ Og) {
    __shared__ __attribute__((aligned(16))) unsigned short Ks[2][64 * 128];  // swizzled (kv, d)
    __shared__ __attribute__((aligned(16))) unsigned short Vs[2][128 * 64];  // swizzled (d, kv)
    const int px = blockIdx.x;
    const int p = (px & 1) ? (15 - (px >> 1)) : (px >> 1);
    const int bh = blockIdx.y;
    const int b = bh >> 4, h = bh & 15, hk = h >> 1;
    const int tid = threadIdx.x;
    const int w = tid >> 6, lane = tid & 63, ln = lane & 15, quad = lane >> 4;
    const int sg = w >> 2;                    // strip group: 0 -> tile p, 1 -> tile 31-p
    const int wi = w & 3;
    const int tile = sg ? (31 - p) : p;
    const int jdiag = tile;                   // kv-tile index where the causal diagonal falls
    const int qrow0 = tile * 64 + wi * 16;    // this wave's 16 q-rows

    const unsigned short* Kbase = Kg + (size_t)(b * 8 + hk) * TSEQ * HD;
    const unsigned short* Vbase = Vt + (size_t)(b * 8 + hk) * HD * TSEQ;
    const unsigned short* Qh = Q + (size_t)(b * 16 + h) * TSEQ * HD;

    short8 qf[4];
#pragma unroll
    for (int kt = 0; kt < 4; kt++)
        qf[kt] = *(const short8*)(Qh + (size_t)(qrow0 + ln) * HD + kt * 32 + quad * 8);

    f32x4 o[8];
    f32x4 lac = (f32x4){0.f, 0.f, 0.f, 0.f};
#pragma unroll
    for (int ot = 0; ot < 8; ot++) o[ot] = (f32x4){0.f, 0.f, 0.f, 0.f};
    float m_ = -1e30f;

    const int kr = lane >> 4;
    const int kc = lane & 15;
    const int vr = lane >> 3;
    const int vc = lane & 7;

    auto stage_kv = [&](int jt, int bi) {
        const int j0s = jt * 64;
        unsigned short* KsB = Ks[bi];
        unsigned short* VsB = Vs[bi];
#pragma unroll
        for (int c = 0; c < 2; c++) {   // K: LDS[r][c] = K[r][c ^ (r&15)]
            int row = w * 8 + c * 4 + kr;
            glds16(Kbase + (size_t)(j0s + row) * HD + ((kc ^ (row & 15)) * 8),
                   KsB + (w * 8 + c * 4) * 128);
        }
#pragma unroll
        for (int c = 0; c < 2; c++) {   // V^T: LDS[d][c] = V[d][c ^ (d&7)]
            int d = w * 16 + c * 8 + vr;
            glds16(Vbase + (size_t)d * TSEQ + j0s + ((vc ^ (d & 7)) * 8),
                   VsB + (w * 16 + c * 8) * 64);
        }
    };

    // bf16 1.0 fragment for row-sum MFMA (B = all-ones 16x32)
    short8 ones8;
#pragma unroll
    for (int i = 0; i < 8; i++) ones8[i] = (short)0x3F80;

    const int nT = 32 - p;
    stage_kv(0, 0);
    for (int j = 0; j < nT; j++) {
        __syncthreads();                 // drains my glds for buf j&1 (prev iter's prefetch)
        if (j + 1 < nT) stage_kv(j + 1, (j + 1) & 1);
        const unsigned short* KsC = Ks[j & 1];
        const unsigned short* VsC = Vs[j & 1];
        const bool act = sg ? true : (j <= jdiag);
        if (act) {
            // ---- QK^T (Q pre-scaled: s is in exp2 domain) ----
            f32x4 s[4];
#pragma unroll
            for (int kb = 0; kb < 4; kb++) s[kb] = (f32x4){0.f, 0.f, 0.f, 0.f};
            __builtin_amdgcn_s_setprio(1);
#pragma unroll
            for (int kt = 0; kt < 4; kt++) {
                short8 kf[4];
#pragma unroll
                for (int kb = 0; kb < 4; kb++)
                    kf[kb] = *(const short8*)(KsC + (kb * 16 + ln) * 128 + (((kt * 4 + quad) ^ ln) * 8));
#pragma unroll
                for (int kb = 0; kb < 4; kb++)
                    s[kb] = __builtin_amdgcn_mfma_f32_16x16x32_bf16(kf[kb], qf[kt], s[kb], 0, 0, 0);
            }
            __builtin_amdgcn_s_setprio(0);
            // ---- softmax: defer-max (THR=8), shuffle-free common path ----
            float mk[4];
            if (j == jdiag) {
                const int qloc = wi * 16 + ln;
#pragma unroll
                for (int kb = 0; kb < 4; kb++) {
#pragma unroll
                    for (int r = 0; r < 4; r++) {
                        int kvloc = kb * 16 + quad * 4 + r;
                        if (kvloc > qloc) s[kb][r] = -1e30f;
                    }
                    mk[kb] = fmaxf(fmaxf(s[kb][0], s[kb][1]), fmaxf(s[kb][2], s[kb][3]));
                }
            } else {
#pragma unroll
                for (int kb = 0; kb < 4; kb++)
                    mk[kb] = fmaxf(fmaxf(s[kb][0], s[kb][1]), fmaxf(s[kb][2], s[kb][3]));
            }
            float mx = fmaxf(fmaxf(mk[0], mk[1]), fmaxf(mk[2], mk[3]));
            float mn = m_;
            bool needR = false;
            float alpha = 1.f;
            if (!__all(mx <= mn + 8.0f)) {
                mx = fmaxf(mx, __shfl_xor(mx, 16));
                mx = fmaxf(mx, __shfl_xor(mx, 32));
                mn = fmaxf(m_, mx);
                alpha = __builtin_exp2f(m_ - mn);
                m_ = mn;
                needR = true;
            }
            // ---- P -> bf16 packed, then VALU quad-crossbar (no LDS) ----
            unsigned int u[8];
#pragma unroll
            for (int kb = 0; kb < 4; kb++) {
                float p0 = __builtin_exp2f(s[kb][0] - mn);
                float p1 = __builtin_exp2f(s[kb][1] - mn);
                float p2 = __builtin_exp2f(s[kb][2] - mn);
                float p3 = __builtin_exp2f(s[kb][3] - mn);
                u[kb * 2 + 0] = cvtpk(p0, p1);   // kv = 16kb + 4*quad + {0,1}, q = ln
                u[kb * 2 + 1] = cvtpk(p2, p3);   // kv = 16kb + 4*quad + {2,3}
            }
            pl32(u[0], u[2]); pl16(u[0], u[2]);   // -> pf0 t0, t2
            pl32(u[1], u[3]); pl16(u[1], u[3]);   // -> pf0 t1, t3
            pl32(u[4], u[6]); pl16(u[4], u[6]);   // -> pf1 t0, t2
            pl32(u[5], u[7]); pl16(u[5], u[7]);   // -> pf1 t1, t3
            union { unsigned int uu[4]; short8 s8; } P0, P1;
            P0.uu[0] = u[0]; P0.uu[1] = u[1]; P0.uu[2] = u[2]; P0.uu[3] = u[3];
            P1.uu[0] = u[4]; P1.uu[1] = u[5]; P1.uu[2] = u[6]; P1.uu[3] = u[7];
            short8 pf0 = P0.s8;   // P[kv = 8*quad + {0..7}][q = ln]
            short8 pf1 = P1.s8;   // P[kv = 32 + 8*quad + {0..7}][q = ln]
            // ---- rescale O and l (uniform branch, rare after first tile) ----
            if (needR) {
#pragma unroll
                for (int ot = 0; ot < 8; ot++)
#pragma unroll
                    for (int r = 0; r < 4; r++) o[ot][r] *= alpha;
#pragma unroll
                for (int r = 0; r < 4; r++) lac[r] *= alpha;
            }
            // ---- PV + row-sum; operand-swapped (O: col=q=ln, rows=d) ----
            __builtin_amdgcn_s_setprio(1);
            lac = __builtin_amdgcn_mfma_f32_16x16x32_bf16(ones8, pf0, lac, 0, 0, 0);
            lac = __builtin_amdgcn_mfma_f32_16x16x32_bf16(ones8, pf1, lac, 0, 0, 0);
#pragma unroll
            for (int ot = 0; ot < 8; ot++) {
                short8 vf0 = *(const short8*)(VsC + (ot * 16 + ln) * 64 + ((quad ^ (ln & 7)) * 8));
                short8 vf1 = *(const short8*)(VsC + (ot * 16 + ln) * 64 + (((4 + quad) ^ (ln & 7)) * 8));
                o[ot] = __builtin_amdgcn_mfma_f32_16x16x32_bf16(vf0, pf0, o[ot], 0, 0, 0);
                o[ot] = __builtin_amdgcn_mfma_f32_16x16x32_bf16(vf1, pf1, o[ot], 0, 0, 0);
            }
            __builtin_amdgcn_s_setprio(0);
        }
    }
    // epilogue: lane has q = qrow0+ln; regs are 4 consecutive d -> 8B stores
    float inv = 1.0f / lac[0];
    size_t rowoff = ((size_t)(b * TSEQ + qrow0 + ln)) * QOUT + h * 128 + quad * 4;
#pragma unroll
    for (int ot = 0; ot < 8; ot++) {
        unsigned long long pk =
            (unsigned long long)cvtpk(o[ot][0] * inv, o[ot][1] * inv) |
            ((unsigned long long)cvtpk(o[ot][2] * inv, o[ot][3] * inv) << 32);
        *(unsigned long long*)(Og + rowoff + ot * 16) = pk;
    }
}

extern "C" void kernel_launch(void* const* d_in, const int* in_sizes, int n_in,
                              void* d_out, int out_size, void* d_ws, size_t ws_size,
                              hipStream_t stream) {
    (void)in_sizes; (void)n_in; (void)out_size;
    const float* x  = (const float*)d_in[0];
    const float* Wq = (const float*)d_in[1];
    const float* Wk = (const float*)d_in[2];
    const float* Wv = (const float*)d_in[3];
    const float* Wo = (const float*)d_in[4];
    const float* qw = (const float*)d_in[5];
    const float* kw = (const float*)d_in[6];

    char* ws = (char*)d_ws;
    const size_t MB = 1024 * 1024;
    unsigned short* Wt   = (unsigned short*)(ws);            // 8 MB
    unsigned short* Wot  = (unsigned short*)(ws + 8 * MB);   // 4 MB
    unsigned short* QKVb = (unsigned short*)(ws + 12 * MB);  // 32 MB (bf16)
    unsigned short* xb   = (unsigned short*)(ws + 44 * MB);  // 8 MB
    unsigned short* Qb   = (unsigned short*)(ws + 52 * MB);  // 16 MB
    unsigned short* Kb   = (unsigned short*)(ws + 68 * MB);  // 8 MB
    unsigned short* Vtb  = (unsigned short*)(ws + 76 * MB);  // 8 MB
    unsigned short* Ob   = (unsigned short*)(ws + 84 * MB);  // 16 MB
    if (ws_size < 100 * MB) return;

    prep<<<dim3(5632), 256, 0, stream>>>(x, Wq, Wk, Wv, Wo, xb, Wt, Wot);
    gemm8<<<dim3(16, 16), 512, 0, stream>>>(xb, Wt, QKVb, 4096, 4096, 1024);
    nrvt<<<dim3(12800), 256, 0, stream>>>(QKVb, qw, kw, Qb, Kb, Vtb);
    attn<<<dim3(16, 32), 512, 0, stream>>>(Qb, Kb, Vtb, Ob);
    gemm_o<0><<<dim3(16, 32), 256, 0, stream>>>(Ob, Wot, (float*)d_out, 4096, 1024, 2048);
}